// Round 5
// baseline (125.332 us; speedup 1.0000x reference)
//
#include <hip/hip_runtime.h>
#include <hip/hip_bf16.h>

// Problem constants (from reference)
#define MAX_LEN_PAD 2560
#define MIN_LEN_SEG 19
#define MAX_NUM_SEG 108   // segments per batch row
#define B_ROWS      32
#define S_CAND      64
#define N_SEG       3456  // B_ROWS * MAX_NUM_SEG
#define SEG_PER_THR 6     // 576 threads x 6 = 3456
#define NTHR        640   // 32 out-rows x 20 float4

// Single fused kernel: every block redundantly computes the segment scan in
// LDS (inputs are 28 KB -> L2-resident), then does the row-parallel gather.
// Eliminates the separate scan dispatch, the ws round-trip, and the
// dependent-global binary search of earlier rounds.
__global__ __launch_bounds__(NTHR) void interp_fused_kernel(
    const float* __restrict__ x, const int* __restrict__ len_seq,
    const float* __restrict__ scales_u, const int* __restrict__ len_seg_raw,
    float* __restrict__ out)
{
    __shared__ int   s_lg[N_SEG];        // lenseg, overwritten in place by gcum
    __shared__ float s_scale[N_SEG];     // raw scales_u
    __shared__ int   s_start[N_SEG + 1]; // global exclusive scan of counts
    __shared__ int   s_rowcum[B_ROWS];   // gcum at each batch row start
    __shared__ int   s_part[16];         // wave partials (10 waves)
    __shared__ int   s_misc[4];          // rows, M
    __shared__ int   s_src[32];          // phase-2: x row per out-row (-1 = zero)
    __shared__ float s_lam[32];

    const int tid  = threadIdx.x;
    const int lane = tid & 63;
    const int wave = tid >> 6;           // 0..9

    // ---- load inputs to LDS (coalesced) ----
    for (int i = tid; i < N_SEG; i += NTHR) {
        s_lg[i]    = len_seg_raw[i] + MIN_LEN_SEG;
        s_scale[i] = scales_u[i];
    }
    __syncthreads();                                         // B1

    // ---- global exclusive cumsum of lenseg (6 segs/thread) ----
    int v[SEG_PER_THR];
    int sum = 0;
    const bool active = tid < N_SEG / SEG_PER_THR;           // tid < 576
    if (active) {
        #pragma unroll
        for (int j = 0; j < SEG_PER_THR; ++j) {
            v[j] = s_lg[tid * SEG_PER_THR + j];
            sum += v[j];
        }
    }
    int incl = sum;
    #pragma unroll
    for (int d = 1; d < 64; d <<= 1) {
        int o = __shfl_up(incl, d, 64);
        if (lane >= d) incl += o;
    }
    if (lane == 63) s_part[wave] = incl;
    __syncthreads();                                         // B2
    if (tid == 0) {
        int run = 0;
        #pragma unroll
        for (int w = 0; w < 10; ++w) { int p = s_part[w]; s_part[w] = run; run += p; }
    }
    __syncthreads();                                         // B3
    int gbase = s_part[wave] + incl - sum;   // exclusive gcum at this thread's chunk
    if (active) {
        int run = gbase;
        #pragma unroll
        for (int j = 0; j < SEG_PER_THR; ++j) { s_lg[tid * SEG_PER_THR + j] = run; run += v[j]; }
    }
    __syncthreads();                                         // B4
    if (tid < B_ROWS) s_rowcum[tid] = s_lg[tid * MAX_NUM_SEG];
    __syncthreads();                                         // B5

    // ---- per-segment mask counts (exact fp32 predicate, 6-step binsearch) ----
    int cnt[SEG_PER_THR];
    int csum = 0;
    if (active) {
        const int brow = tid / (MAX_NUM_SEG / SEG_PER_THR);  // t/18: batch row (6|108)
        const int ls   = len_seq[brow];
        int run = gbase;
        #pragma unroll
        for (int j = 0; j < SEG_PER_THR; ++j) {
            int k = tid * SEG_PER_THR + j;
            float scale = s_scale[k] + 0.5f;
            int off = run - s_rowcum[brow];                  // offset within batch row
            run += v[j];
            int T = v[j] - 1;
            int lim = ls - 1 - off;
            if (lim < T) T = lim;
            float Tf = (float)T;
            int lo = 0, hi = S_CAND;
            while (lo < hi) {
                int mid = (lo + hi) >> 1;
                // exact IEEE div + floor, bitwise-matches reference predicate
                if (floorf((float)mid / scale) < Tf) lo = mid + 1; else hi = mid;
            }
            cnt[j] = lo; csum += lo;
        }
    }

    // ---- global exclusive scan of counts -> s_start ----
    int cincl = csum;
    #pragma unroll
    for (int d = 1; d < 64; d <<= 1) {
        int o = __shfl_up(cincl, d, 64);
        if (lane >= d) cincl += o;
    }
    if (lane == 63) s_part[wave] = cincl;
    __syncthreads();                                         // B6
    if (tid == 0) {
        int run = 0;
        #pragma unroll
        for (int w = 0; w < 10; ++w) { int p = s_part[w]; s_part[w] = run; run += p; }
        s_start[N_SEG] = run;
        int rows = run / B_ROWS;
        int M = rows < MAX_LEN_PAD ? rows : MAX_LEN_PAD;
        s_misc[0] = rows;
        s_misc[1] = M;
    }
    __syncthreads();                                         // B7
    if (active) {
        int run = s_part[wave] + cincl - csum;
        #pragma unroll
        for (int j = 0; j < SEG_PER_THR; ++j) { s_start[tid * SEG_PER_THR + j] = run; run += cnt[j]; }
    }
    __syncthreads();                                         // B8

    // ---- phase 2: row-parallel gather. threads 0..31 resolve their row ----
    const int rows = s_misc[0];
    const int M    = s_misc[1];
    if (tid < 32) {
        int r = blockIdx.x * 32 + tid;
        int b = r / MAX_LEN_PAD;
        int t = r - b * MAX_LEN_PAD;
        int src = -1;
        float lam = 0.0f;
        if (t < M) {
            int g = b * rows + t;    // compacted index, < total guaranteed
            // first n with s_start[n+1] > g  (12-step LDS binary search)
            int lo = 0, hi = N_SEG;
            while (lo < hi) {
                int mid = (lo + hi) >> 1;
                if (s_start[mid + 1] <= g) lo = mid + 1; else hi = mid;
            }
            int n = lo;
            int s = g - s_start[n];
            float scale = s_scale[n] + 0.5f;
            float q  = (float)s / scale;     // exact IEEE, matches ref
            float fi = floorf(q);
            lam = q - fi;
            int nrow = n / MAX_NUM_SEG;      // segment's batch row (ref: elem_batch)
            int off  = s_lg[n] - s_rowcum[nrow];
            int i_fl = (int)fi + off;
            if (i_fl > MAX_LEN_PAD - 2) i_fl = MAX_LEN_PAD - 2;  // ref clip (no-op for kept)
            src = nrow * MAX_LEN_PAD + i_fl;
        }
        s_src[tid] = src;
        s_lam[tid] = lam;
    }
    __syncthreads();                                         // B9

    const int rl = tid / 20;         // 0..31
    const int q4 = tid - rl * 20;    // 0..19
    const int r  = blockIdx.x * 32 + rl;
    const int   src = s_src[rl];
    const float lam = s_lam[rl];

    float4 res;
    if (src < 0) {
        res = make_float4(0.f, 0.f, 0.f, 0.f);
    } else {
        const float4* x4 = (const float4*)x;
        float4 a = x4[src * 20 + q4];
        float4 c = x4[src * 20 + 20 + q4];
        float om = 1.0f - lam;
        res.x = om * a.x + lam * c.x;
        res.y = om * a.y + lam * c.y;
        res.z = om * a.z + lam * c.z;
        res.w = om * a.w + lam * c.w;
    }
    ((float4*)out)[r * 20 + q4] = res;
}

extern "C" void kernel_launch(void* const* d_in, const int* in_sizes, int n_in,
                              void* d_out, int out_size, void* d_ws, size_t ws_size,
                              hipStream_t stream) {
    (void)in_sizes; (void)n_in; (void)out_size; (void)d_ws; (void)ws_size;
    const float* x           = (const float*)d_in[0];
    const int*   len_seq     = (const int*)d_in[1];
    const float* scales_u    = (const float*)d_in[2];
    const int*   len_seg_raw = (const int*)d_in[3];
    float* out = (float*)d_out;

    // 32*2560 out rows / 32 rows per block = 2560 blocks, one fused dispatch
    interp_fused_kernel<<<2560, NTHR, 0, stream>>>(x, len_seq, scales_u, len_seg_raw, out);
}

// Round 6
// 90.869 us; speedup vs baseline: 1.3793x; 1.3793x over previous
//
#include <hip/hip_runtime.h>
#include <hip/hip_bf16.h>

// Problem constants (from reference)
#define MAX_LEN_PAD 2560
#define MIN_LEN_SEG 19
#define MAX_NUM_SEG 108   // segments per batch row
#define B_ROWS      32
#define S_CAND      64
#define N_SEG       3456  // B_ROWS * MAX_NUM_SEG

// ws layout (ints)
#define WS_META      0                 // [0]=rows, [1]=M
#define WS_SEGSTART  16                // 3457 ints (+pad)
#define WS_SEGOFF    3504              // 3456 ints
#define WS_TABLE     8192              // int2 per output row: 81920 * 2 ints

// K1: single block, 576 threads, 5 barriers. Each thread owns 6 consecutive
// segments (18 threads per batch row — rows align to thread boundaries).
// Computes global cumsum of len_seg, per-segment in-row offsets, per-segment
// mask counts (prefix property -> 6-step binsearch with the reference's exact
// IEEE fp32 predicate), global exclusive scan of counts. Writes ws.
__global__ __launch_bounds__(576) void k1_scan(
    const int* __restrict__ len_seq, const float* __restrict__ scales_u,
    const int* __restrict__ len_seg_raw, int* __restrict__ ws)
{
    __shared__ int s_part[16];          // 9 wave partials
    __shared__ int s_rowcum[B_ROWS];    // gcum at each batch-row start

    const int tid  = threadIdx.x;       // 0..575
    const int lane = tid & 63;
    const int wave = tid >> 6;          // 0..8
    const int brow = tid / 18;          // batch row of this thread's 6 segments

    // thread-local loads (no LDS staging needed)
    int v[6]; float sc[6];
    int sum = 0;
    #pragma unroll
    for (int j = 0; j < 6; ++j) {
        int k = tid * 6 + j;
        v[j]  = len_seg_raw[k] + MIN_LEN_SEG;
        sc[j] = scales_u[k];
        sum  += v[j];
    }

    // global exclusive cumsum of lenseg
    int incl = sum;
    #pragma unroll
    for (int d = 1; d < 64; d <<= 1) {
        int o = __shfl_up(incl, d, 64);
        if (lane >= d) incl += o;
    }
    if (lane == 63) s_part[wave] = incl;
    __syncthreads();                                     // B1
    if (tid == 0) {
        int run = 0;
        #pragma unroll
        for (int w = 0; w < 9; ++w) { int p = s_part[w]; s_part[w] = run; run += p; }
    }
    __syncthreads();                                     // B2
    const int gbase = s_part[wave] + incl - sum;
    if (tid % 18 == 0) s_rowcum[brow] = gbase;           // row starts align to threads
    __syncthreads();                                     // B3

    // per-segment offsets + counts
    const int ls = len_seq[brow];
    const int rowc = s_rowcum[brow];
    int cnt[6]; int csum = 0;
    int* seg_off = ws + WS_SEGOFF;
    {
        int run = gbase;
        #pragma unroll
        for (int j = 0; j < 6; ++j) {
            int off = run - rowc;
            seg_off[tid * 6 + j] = off;
            run += v[j];
            float scale = sc[j] + 0.5f;
            int T = v[j] - 1;
            int lim = ls - 1 - off;
            if (lim < T) T = lim;
            float Tf = (float)T;
            int lo = 0, hi = S_CAND;
            while (lo < hi) {
                int mid = (lo + hi) >> 1;
                // exact IEEE div + floor: bitwise-matches reference predicate
                if (floorf((float)mid / scale) < Tf) lo = mid + 1; else hi = mid;
            }
            cnt[j] = lo; csum += lo;
        }
    }

    // global exclusive scan of counts
    int cincl = csum;
    #pragma unroll
    for (int d = 1; d < 64; d <<= 1) {
        int o = __shfl_up(cincl, d, 64);
        if (lane >= d) cincl += o;
    }
    if (lane == 63) s_part[wave] = cincl;
    __syncthreads();                                     // B4
    if (tid == 0) {
        int run = 0;
        #pragma unroll
        for (int w = 0; w < 9; ++w) { int p = s_part[w]; s_part[w] = run; run += p; }
        int total = run;
        ws[WS_SEGSTART + N_SEG] = total;
        int rows = total / B_ROWS;
        int M = rows < MAX_LEN_PAD ? rows : MAX_LEN_PAD;
        ws[WS_META + 0] = rows;
        ws[WS_META + 1] = M;
    }
    __syncthreads();                                     // B5
    {
        int run = s_part[wave] + cincl - csum;
        int* seg_start = ws + WS_SEGSTART;
        #pragma unroll
        for (int j = 0; j < 6; ++j) { seg_start[tid * 6 + j] = run; run += cnt[j]; }
    }
}

// K2: one wave per segment (432 blocks x 512 threads = 3456 waves).
// The compaction is a bijection: segment n's element s lands at compacted
// index g = seg_start[n]+s -> output row (g/rows, g%rows). Write that row's
// (src_x_row, lam) as int2 into the table — coalesced, L2-resident. Every
// t < M slot is written exactly once; t >= M slots stay poisoned (unread).
__global__ __launch_bounds__(512) void k2_table(
    const float* __restrict__ scales_u, int* __restrict__ ws)
{
    const int n = blockIdx.x * 8 + (threadIdx.x >> 6);   // segment
    const int s = threadIdx.x & 63;
    const int rows = ws[WS_META + 0];
    if (rows <= 0) return;

    const int* seg_start = ws + WS_SEGSTART;
    int s0  = seg_start[n];
    int cnt = seg_start[n + 1] - s0;
    if (s >= cnt) return;

    float scale = scales_u[n] + 0.5f;
    int off = ws[WS_SEGOFF + n];
    int g = s0 + s;
    int b_out = g / rows;                 // runtime div, once per lane
    int t = g - b_out * rows;
    if (b_out < B_ROWS && t < MAX_LEN_PAD) {
        float q  = (float)s / scale;      // exact IEEE, matches ref
        float fi = floorf(q);
        float lam = q - fi;
        int i_fl = (int)fi + off;
        if (i_fl > MAX_LEN_PAD - 2) i_fl = MAX_LEN_PAD - 2;   // ref clip
        int src = (n / MAX_NUM_SEG) * MAX_LEN_PAD + i_fl;
        ((int2*)(ws + WS_TABLE))[b_out * MAX_LEN_PAD + t] =
            make_int2(src, __float_as_int(lam));
    }
}

// K3: pure gather — no searches, no barriers, no LDS. 2560 blocks x 640 thr,
// one float4 per thread. The 20 lanes of an output row broadcast-read the
// same 8-B table entry (L1), then do coalesced float4 lerp / zero.
__global__ __launch_bounds__(640) void k3_gather(
    const float* __restrict__ x, const int* __restrict__ ws,
    float* __restrict__ out)
{
    const int M = ws[WS_META + 1];
    int flat = blockIdx.x * 640 + threadIdx.x;   // = r*20 + q4
    int r  = flat / 20;                          // magic-mul div
    int q4 = flat - r * 20;
    int t  = r % MAX_LEN_PAD;                    // magic-mul mod

    float4 res = make_float4(0.f, 0.f, 0.f, 0.f);
    if (t < M) {
        int2 e = ((const int2*)(ws + WS_TABLE))[r];
        int src = e.x;
        float lam = __int_as_float(e.y);
        const float4* x4 = (const float4*)x;
        float4 a = x4[src * 20 + q4];
        float4 c = x4[src * 20 + 20 + q4];
        float om = 1.0f - lam;
        res.x = om * a.x + lam * c.x;
        res.y = om * a.y + lam * c.y;
        res.z = om * a.z + lam * c.z;
        res.w = om * a.w + lam * c.w;
    }
    ((float4*)out)[flat] = res;
}

extern "C" void kernel_launch(void* const* d_in, const int* in_sizes, int n_in,
                              void* d_out, int out_size, void* d_ws, size_t ws_size,
                              hipStream_t stream) {
    (void)in_sizes; (void)n_in; (void)out_size; (void)ws_size;
    const float* x           = (const float*)d_in[0];
    const int*   len_seq     = (const int*)d_in[1];
    const float* scales_u    = (const float*)d_in[2];
    const int*   len_seg_raw = (const int*)d_in[3];
    float* out = (float*)d_out;
    int*   ws  = (int*)d_ws;

    k1_scan<<<1, 576, 0, stream>>>(len_seq, scales_u, len_seg_raw, ws);
    k2_table<<<432, 512, 0, stream>>>(scales_u, ws);
    k3_gather<<<2560, 640, 0, stream>>>(x, ws, out);
}